// Round 13
// baseline (264.808 us; speedup 1.0000x reference)
//
#include <hip/hip_runtime.h>
#include <hip/hip_bf16.h>

#define D_MODEL 768
#define D_INNER 1536
#define D_STATE 16
#define DT_RANK 48
#define SEQ 2048
#define NC 32            // scan chunks
#define LC (SEQ / NC)    // 64 timesteps per chunk
#define DN (D_INNER * D_STATE)  // 24576 (d,n) pairs
#define KS 8             // GEMM2 split-K ways
#define KCH (D_INNER / KS)  // 192

typedef float f32x4 __attribute__((ext_vector_type(4)));
typedef short bf16x8 __attribute__((ext_vector_type(8)));

typedef const __attribute__((address_space(1))) unsigned int* gas_u32;
typedef __attribute__((address_space(3))) unsigned int* las_u32;

// async global->LDS, 16B per lane; LDS dest = uniform base + lane*16 (m104)
__device__ __forceinline__ void gload16(const void* g, void* l) {
  __builtin_amdgcn_global_load_lds((gas_u32)g, (las_u32)l, 16, 0, 0);
}

// Butterfly all-reduce (sum) over each 16-lane group, pure DPP (no LDS ops).
__device__ __forceinline__ float dpp_radd16(float v) {
  int x;
  x = __builtin_amdgcn_update_dpp(0, __float_as_int(v), 0xB1, 0xF, 0xF, true);  // quad_perm xor1
  v += __int_as_float(x);
  x = __builtin_amdgcn_update_dpp(0, __float_as_int(v), 0x4E, 0xF, 0xF, true);  // quad_perm xor2
  v += __int_as_float(x);
  x = __builtin_amdgcn_update_dpp(0, __float_as_int(v), 0x141, 0xF, 0xF, true); // row_half_mirror
  v += __int_as_float(x);
  x = __builtin_amdgcn_update_dpp(0, __float_as_int(v), 0x140, 0xF, 0xF, true); // row_mirror
  v += __int_as_float(x);
  return v;
}

// round-to-nearest-even fp32 -> bf16 bits
__device__ __forceinline__ ushort f2bf_bits(float f) {
  uint u = __float_as_uint(f);
  u += 0x7FFFu + ((u >> 16) & 1u);
  return (ushort)(u >> 16);
}
__device__ __forceinline__ float bf_bits2f(ushort b) {
  return __uint_as_float(((uint)b) << 16);
}

__device__ __forceinline__ void split_vec4(const float* __restrict__ src,
                                           ushort* __restrict__ hi,
                                           ushort* __restrict__ lo, int idx) {
  const float4 v = ((const float4*)src)[idx];
  const float f[4] = {v.x, v.y, v.z, v.w};
  ushort4 h, l;
  ushort* hp = (ushort*)&h;
  ushort* lp = (ushort*)&l;
#pragma unroll
  for (int j = 0; j < 4; ++j) {
    const ushort hb = f2bf_bits(f[j]);
    hp[j] = hb;
    lp[j] = f2bf_bits(f[j] - bf_bits2f(hb));
  }
  ((ushort4*)hi)[idx] = h;
  ((ushort4*)lo)[idx] = l;
}

// ---------------------------------------------------------------------------
// Fused fp32 -> (hi,lo) bf16 split of three tensors (x, W_in, W_out).
// ---------------------------------------------------------------------------
__global__ __launch_bounds__(256) void split3_bf16_kernel(
    const float* __restrict__ s0, ushort* __restrict__ h0, ushort* __restrict__ l0, int n0v,
    const float* __restrict__ s1, ushort* __restrict__ h1, ushort* __restrict__ l1, int n1v,
    const float* __restrict__ s2, ushort* __restrict__ h2, ushort* __restrict__ l2) {
  int idx = blockIdx.x * 256 + threadIdx.x;
  if (idx < n0v) {
    split_vec4(s0, h0, l0, idx);
  } else if (idx < n0v + n1v) {
    split_vec4(s1, h1, l1, idx - n0v);
  } else {
    split_vec4(s2, h2, l2, idx - n0v - n1v);
  }
}

// ---------------------------------------------------------------------------
// MFMA GEMM on pre-split bf16 hi/lo operands, global_load_lds staging with
// XOR-swizzle (both-sides pairing): LDS dest linear, global source column
// pre-swizzled slot^=(row&7), fragment read applies the same involution.
// C = Ahi·Bhi^T + Ahi·Blo^T + Alo·Bhi^T   (3-term Ootomo split)
// ---------------------------------------------------------------------------
template <int BM, int BN>
__global__ __launch_bounds__(256) void gemm_mfma_presplit(
    const ushort* __restrict__ Ah, const ushort* __restrict__ Al, int lda,
    const ushort* __restrict__ Bh, const ushort* __restrict__ Bl, int ldb,
    float* __restrict__ C, int ldc, int K) {
  __shared__ __align__(16) ushort As_hi[BM * 64];
  __shared__ __align__(16) ushort As_lo[BM * 64];
  __shared__ __align__(16) ushort Bs_hi[BN * 64];
  __shared__ __align__(16) ushort Bs_lo[BN * 64];

  const int tid = threadIdx.x;
  const int lane = tid & 63;
  const int wave = tid >> 6;
  const int wbase = tid & 192;  // wave*64, uniform within wave
  const int m0 = blockIdx.y * BM;
  const int n0 = blockIdx.x * BN;

  constexpr int FM = BM / 32;
  constexpr int FN = BN / 32;
  const int wm0 = (wave >> 1) * (BM / 2);
  const int wn0 = (wave & 1) * (BN / 2);
  const int fr = lane & 15;
  const int kg = lane >> 4;

  f32x4 acc[FM][FN] = {};

  for (int k0 = 0; k0 < K; k0 += 64) {
#pragma unroll
    for (int i = 0; i < BM / 32; ++i) {
      const int slot = i * 256 + tid;
      const int row = slot >> 3;
      const int c8 = ((slot & 7) ^ (row & 7)) << 3;  // pre-swizzled source col
      const size_t g = (size_t)(m0 + row) * lda + k0 + c8;
      const int lb = (i * 256 + wbase) * 8;  // wave-uniform LDS base slot
      gload16(&Ah[g], &As_hi[lb]);
      gload16(&Al[g], &As_lo[lb]);
    }
#pragma unroll
    for (int i = 0; i < BN / 32; ++i) {
      const int slot = i * 256 + tid;
      const int row = slot >> 3;
      const int c8 = ((slot & 7) ^ (row & 7)) << 3;
      const size_t g = (size_t)(n0 + row) * ldb + k0 + c8;
      const int lb = (i * 256 + wbase) * 8;
      gload16(&Bh[g], &Bs_hi[lb]);
      gload16(&Bl[g], &Bs_lo[lb]);
    }
    __syncthreads();

#pragma unroll
    for (int k2 = 0; k2 < 64; k2 += 32) {
      const int gslot = (k2 >> 3) + kg;  // logical 16B slot within the row
      bf16x8 ah[FM], al[FM];
#pragma unroll
      for (int m = 0; m < FM; ++m) {
        const int row = wm0 + m * 16 + fr;
        const int base = row * 64 + ((gslot ^ (row & 7)) << 3);
        ah[m] = *(const bf16x8*)&As_hi[base];
        al[m] = *(const bf16x8*)&As_lo[base];
      }
#pragma unroll
      for (int n = 0; n < FN; ++n) {
        const int row = wn0 + n * 16 + fr;
        const int base = row * 64 + ((gslot ^ (row & 7)) << 3);
        const bf16x8 bh = *(const bf16x8*)&Bs_hi[base];
        const bf16x8 bl = *(const bf16x8*)&Bs_lo[base];
#pragma unroll
        for (int m = 0; m < FM; ++m) {
          acc[m][n] = __builtin_amdgcn_mfma_f32_16x16x32_bf16(ah[m], bh, acc[m][n], 0, 0, 0);
          acc[m][n] = __builtin_amdgcn_mfma_f32_16x16x32_bf16(ah[m], bl, acc[m][n], 0, 0, 0);
          acc[m][n] = __builtin_amdgcn_mfma_f32_16x16x32_bf16(al[m], bh, acc[m][n], 0, 0, 0);
        }
      }
    }
    __syncthreads();
  }

  // C/D layout: col = lane&15, row = (lane>>4)*4 + reg   [m89]
#pragma unroll
  for (int m = 0; m < FM; ++m) {
#pragma unroll
    for (int n = 0; n < FN; ++n) {
      const int row = m0 + wm0 + m * 16 + (lane >> 4) * 4;
      const int col = n0 + wn0 + n * 16 + (lane & 15);
#pragma unroll
      for (int r = 0; r < 4; ++r) C[(row + r) * ldc + col] = acc[m][n][r];
    }
  }
}

// ---------------------------------------------------------------------------
// GEMM2 split-K, atomic accumulate: xdbl += xbc[:, kchunk] @ W_x[:, kchunk]^T
// xdbl is zeroed by conv_silu's tail. Grid (SEQ/64, KS).
// ---------------------------------------------------------------------------
__global__ __launch_bounds__(256) void gemm2_splitk(
    const float* __restrict__ A,   // xbc (SEQ, D_INNER)
    const float* __restrict__ B,   // W_x (80, D_INNER)
    float* __restrict__ xdbl) {    // (SEQ, 80), pre-zeroed
  __shared__ __align__(16) float As[16][68];
  __shared__ __align__(16) float Bs[16][84];

  const int tid = threadIdx.x;
  const int tx = tid & 15;
  const int ty = tid >> 4;
  const int m0 = blockIdx.x * 64;
  const int kbase = blockIdx.y * KCH;

  float acc[4][5] = {};

  for (int k0 = 0; k0 < KCH; k0 += 16) {
    {  // stage A 64x16
      const int am = tid >> 2;
      const int ak = (tid & 3) << 2;
      const float4 av = *(const float4*)&A[(m0 + am) * D_INNER + kbase + k0 + ak];
      As[ak + 0][am] = av.x;
      As[ak + 1][am] = av.y;
      As[ak + 2][am] = av.z;
      As[ak + 3][am] = av.w;
    }
    // stage B 80x16
    for (int f = tid; f < 80 * 4; f += 256) {
      const int row = f >> 2;
      const int kk = (f & 3) << 2;
      const float4 bv = *(const float4*)&B[row * D_INNER + kbase + k0 + kk];
      Bs[kk + 0][row] = bv.x;
      Bs[kk + 1][row] = bv.y;
      Bs[kk + 2][row] = bv.z;
      Bs[kk + 3][row] = bv.w;
    }
    __syncthreads();

#pragma unroll
    for (int k = 0; k < 16; ++k) {
      const float4 a4 = *(const float4*)&As[k][ty * 4];
      const float a[4] = {a4.x, a4.y, a4.z, a4.w};
      float b[5];
#pragma unroll
      for (int j = 0; j < 5; ++j) b[j] = Bs[k][tx + 16 * j];
#pragma unroll
      for (int i = 0; i < 4; ++i)
#pragma unroll
        for (int j = 0; j < 5; ++j) acc[i][j] = fmaf(a[i], b[j], acc[i][j]);
    }
    __syncthreads();
  }

#pragma unroll
  for (int i = 0; i < 4; ++i)
#pragma unroll
    for (int j = 0; j < 5; ++j)
      __hip_atomic_fetch_add(&xdbl[(m0 + ty * 4 + i) * 80 + tx + 16 * j],
                             acc[i][j], __ATOMIC_RELAXED,
                             __HIP_MEMORY_SCOPE_AGENT);
}

// ---------------------------------------------------------------------------
// Depthwise causal conv (width 4) + bias + SiLU, vectorized x4 channels.
// Tail: zero xdbl (2048*80 floats == 640 blocks * 256 threads exactly).
// ---------------------------------------------------------------------------
__global__ __launch_bounds__(256) void conv_silu_kernel(
    const float* __restrict__ xz, const float* __restrict__ cw,
    const float* __restrict__ cb, float* __restrict__ xbc,
    float* __restrict__ xdbl) {
  const int idx = blockIdx.x * 256 + threadIdx.x;  // < SEQ * D_INNER/4
  if (blockIdx.x < 640) xdbl[blockIdx.x * 256 + threadIdx.x] = 0.f;
  const int t = idx / (D_INNER / 4);
  const int d = (idx - t * (D_INNER / 4)) * 4;
  const float4 w0 = *(const float4*)&cw[(d + 0) * 4];
  const float4 w1 = *(const float4*)&cw[(d + 1) * 4];
  const float4 w2 = *(const float4*)&cw[(d + 2) * 4];
  const float4 w3 = *(const float4*)&cw[(d + 3) * 4];
  float4 acc = *(const float4*)&cb[d];
#pragma unroll
  for (int j = 0; j < 4; ++j) {
    const int tt = t + j - 3;
    if (tt >= 0) {
      const float4 xv = *(const float4*)&xz[tt * (2 * D_INNER) + d];
      acc.x = fmaf(xv.x, ((const float*)&w0)[j], acc.x);
      acc.y = fmaf(xv.y, ((const float*)&w1)[j], acc.y);
      acc.z = fmaf(xv.z, ((const float*)&w2)[j], acc.z);
      acc.w = fmaf(xv.w, ((const float*)&w3)[j], acc.w);
    }
  }
  float4 r;
  r.x = acc.x / (1.f + __expf(-acc.x));
  r.y = acc.y / (1.f + __expf(-acc.y));
  r.z = acc.z / (1.f + __expf(-acc.z));
  r.w = acc.w / (1.f + __expf(-acc.w));
  *(float4*)&xbc[t * D_INNER + d] = r;
}

// ---------------------------------------------------------------------------
// Fused dt tile: stage xdbl[t0..t0+63, 0:48] + W_dt[d0..d0+15] into scratch,
// compute dt_s[ch][t] = softplus(dot48 + b_dt). scratch 'uni' >= 4112 floats.
// Two internal barriers; uni is free for reuse on return.
// ---------------------------------------------------------------------------
__device__ __forceinline__ void compute_dt_tile(
    const float* __restrict__ xdbl, const float* __restrict__ W_dt,
    const float* __restrict__ b_dt, int t0, int d0, int tid,
    float* __restrict__ uni, float (*dt_s)[68]) {
  float (*xd)[52] = (float(*)[52])uni;     // 64 x 52 (padded)
  float* wdt = uni + 64 * 52;              // 16 x 48
  float* bd = wdt + 16 * 48;               // 16
#pragma unroll
  for (int i = 0; i < 3; ++i) {            // 768 float4 slots, 3/thread
    const int s = i * 256 + tid;
    const int row = s / 12;
    const int c4 = (s - row * 12) * 4;
    *(float4*)&xd[row][c4] = *(const float4*)&xdbl[(t0 + row) * 80 + c4];
  }
  if (tid < 192) {
    const int row = tid / 12;
    const int c4 = (tid - row * 12) * 4;
    *(float4*)&wdt[row * 48 + c4] = *(const float4*)&W_dt[(d0 + row) * 48 + c4];
  } else if (tid < 208) {
    bd[tid - 192] = b_dt[d0 + tid - 192];
  }
  __syncthreads();

  const int ch = tid >> 4, tg = tid & 15;
  float4 w[12];
#pragma unroll
  for (int i = 0; i < 12; ++i) w[i] = *(const float4*)&wdt[ch * 48 + i * 4];
  const float bias = bd[ch];
#pragma unroll
  for (int j = 0; j < 4; ++j) {
    const int t = tg + 16 * j;             // t stride 1 across lanes: 2-way banks
    float acc = 0.f;
#pragma unroll
    for (int i = 0; i < 12; ++i) {
      const float4 xv = *(const float4*)&xd[t][i * 4];
      acc = fmaf(xv.x, w[i].x, acc);
      acc = fmaf(xv.y, w[i].y, acc);
      acc = fmaf(xv.z, w[i].z, acc);
      acc = fmaf(xv.w, w[i].w, acc);
    }
    acc += bias;
    dt_s[ch][t] = (acc > 20.f) ? acc : log1pf(__expf(acc));
  }
  __syncthreads();  // dt_s ready; xd/wdt scratch reusable after this
}

// ---------------------------------------------------------------------------
// Chunked selective scan, phase 1 (fused dt): per (chunk, d-group) local scan
// from h=0, emitting per-(d,n) dA-product and local final state.
// ---------------------------------------------------------------------------
__global__ __launch_bounds__(256) void scan_part1(
    const float* __restrict__ xdbl, const float* __restrict__ xbc,
    const float* __restrict__ W_dt, const float* __restrict__ b_dt,
    const float* __restrict__ A_log,
    float* __restrict__ aprod, float* __restrict__ hloc) {
  __shared__ __align__(16) float smem[16 * 68 + 4112];  // dt_s + union
  float (*dt_s)[68] = (float(*)[68])smem;
  float* uni = smem + 16 * 68;

  const int tid = threadIdx.x;
  const int ch = tid >> 4;
  const int n = tid & 15;
  const int d0 = blockIdx.x * 16;
  const int c = blockIdx.y;
  const int t0 = c * LC;

  const float alog = A_log[(d0 + ch) * D_STATE + n];

  compute_dt_tile(xdbl, W_dt, b_dt, t0, d0, tid, uni, dt_s);

  // phase B staging reuses uni
  float (*xb_s)[68] = (float(*)[68])uni;
  float (*B_s)[68] = (float(*)[68])(uni + 16 * 68);
  for (int f = tid; f < LC * 16; f += 256) {
    const int t = f >> 4, cc = f & 15;
    const int gt = t0 + t;
    xb_s[cc][t] = xbc[gt * D_INNER + d0 + cc];
    B_s[cc][t] = xdbl[gt * 80 + DT_RANK + cc];
  }
  __syncthreads();

  const float Aval = -__expf(alog);
  float h = 0.f, ap = 1.f;
  for (int t4 = 0; t4 < LC; t4 += 4) {
    const float4 dtv = *(const float4*)&dt_s[ch][t4];
    const float4 xbv = *(const float4*)&xb_s[ch][t4];
    const float4 Bv = *(const float4*)&B_s[n][t4];
#pragma unroll
    for (int j = 0; j < 4; ++j) {
      const float sdt = ((const float*)&dtv)[j];
      const float dA = __expf(sdt * Aval);
      h = fmaf(dA, h, sdt * ((const float*)&Bv)[j] * ((const float*)&xbv)[j]);
      ap *= dA;
    }
  }
  const int idx = c * DN + d0 * 16 + tid;
  aprod[idx] = ap;
  hloc[idx] = h;
}

// ---------------------------------------------------------------------------
// Phase 2: sequential combine over the NC chunk summaries per (d,n).
// ---------------------------------------------------------------------------
__global__ __launch_bounds__(256) void scan_combine(
    const float* __restrict__ aprod, const float* __restrict__ hloc,
    float* __restrict__ hstart) {
  const int idx = blockIdx.x * 256 + threadIdx.x;  // < DN
  float hs = 0.f;
#pragma unroll
  for (int c = 0; c < NC; ++c) {
    const float a = aprod[c * DN + idx];
    const float hl = hloc[c * DN + idx];
    hstart[c * DN + idx] = hs;
    hs = fmaf(a, hs, hl);
  }
}

// ---------------------------------------------------------------------------
// Phase 3 (fused dt): re-scan each chunk from its true h_start; DPP butterfly
// reduce; silu(z)/D epilogue in the vectorized writeout; writes ym as bf16
// hi/lo for GEMM4.
// ---------------------------------------------------------------------------
__global__ __launch_bounds__(256) void scan_part3(
    const float* __restrict__ xdbl, const float* __restrict__ xbc,
    const float* __restrict__ xz, const float* __restrict__ W_dt,
    const float* __restrict__ b_dt, const float* __restrict__ A_log,
    const float* __restrict__ Dp, const float* __restrict__ hstart,
    ushort* __restrict__ ym_hi, ushort* __restrict__ ym_lo) {
  __shared__ __align__(16) float smem[16 * 68 + LC * 16 + 4112];
  float (*dt_s)[68] = (float(*)[68])smem;
  float (*y_s)[16] = (float(*)[16])(smem + 16 * 68);
  float* uni = smem + 16 * 68 + LC * 16;

  const int tid = threadIdx.x;
  const int ch = tid >> 4;
  const int n = tid & 15;
  const int d0 = blockIdx.x * 16;
  const int c = blockIdx.y;
  const int t0 = c * LC;

  // early loads: h_start, A_log, z (writeout-only), D
  float h = hstart[c * DN + d0 * 16 + tid];
  const float alog = A_log[(d0 + ch) * D_STATE + n];
  float zpf[4], dpf[4];
#pragma unroll
  for (int u = 0; u < 4; ++u) {
    const int f = u * 256 + tid;
    const int t = f >> 4, cc = f & 15;
    zpf[u] = xz[(size_t)(t0 + t) * (2 * D_INNER) + D_INNER + d0 + cc];
    dpf[u] = Dp[d0 + cc];
  }

  compute_dt_tile(xdbl, W_dt, b_dt, t0, d0, tid, uni, dt_s);

  // phase B staging reuses uni
  float (*xb_s)[68] = (float(*)[68])uni;
  float (*B_s)[68] = (float(*)[68])(uni + 16 * 68);
  float (*C_s)[68] = (float(*)[68])(uni + 32 * 68);
  for (int f = tid; f < LC * 16; f += 256) {
    const int t = f >> 4, cc = f & 15;
    const int gt = t0 + t;
    xb_s[cc][t] = xbc[gt * D_INNER + d0 + cc];
    B_s[cc][t] = xdbl[gt * 80 + DT_RANK + cc];
    C_s[cc][t] = xdbl[gt * 80 + DT_RANK + D_STATE + cc];
  }
  __syncthreads();

  const float Aval = -__expf(alog);

  for (int t4 = 0; t4 < LC; t4 += 4) {
    const float4 dtv = *(const float4*)&dt_s[ch][t4];
    const float4 xbv = *(const float4*)&xb_s[ch][t4];
    const float4 Bv = *(const float4*)&B_s[n][t4];
    const float4 Cv = *(const float4*)&C_s[n][t4];
#pragma unroll
    for (int j = 0; j < 4; ++j) {
      const float sdt = ((const float*)&dtv)[j];
      const float dA = __expf(sdt * Aval);
      h = fmaf(dA, h, sdt * ((const float*)&Bv)[j] * ((const float*)&xbv)[j]);
      const float p = dpp_radd16(h * ((const float*)&Cv)[j]);
      if (n == 0) y_s[t4 + j][ch] = p;
    }
  }
  __syncthreads();

  // writeout: apply +xb*D and *silu(z), split to bf16 hi/lo
#pragma unroll
  for (int u = 0; u < 4; ++u) {
    const int f = u * 256 + tid;
    const int t = f >> 4, cc = f & 15;
    const int gt = t0 + t;
    const float zz = zpf[u];
    const float sig = 1.f / (1.f + __expf(-zz));
    const float v = (y_s[t][cc] + xb_s[cc][t] * dpf[u]) * (zz * sig);
    const ushort hb = f2bf_bits(v);
    const int gidx = gt * D_INNER + d0 + cc;
    ym_hi[gidx] = hb;
    ym_lo[gidx] = f2bf_bits(v - bf_bits2f(hb));
  }
}

// ---------------------------------------------------------------------------
extern "C" void kernel_launch(void* const* d_in, const int* in_sizes, int n_in,
                              void* d_out, int out_size, void* d_ws,
                              size_t ws_size, hipStream_t stream) {
  const float* x = (const float*)d_in[0];       // (2048, 768)
  const float* W_in = (const float*)d_in[1];    // (3072, 768)
  const float* conv_w = (const float*)d_in[2];  // (1536, 1, 4)
  const float* conv_b = (const float*)d_in[3];  // (1536,)
  const float* W_x = (const float*)d_in[4];     // (80, 1536)
  const float* W_dt = (const float*)d_in[5];    // (1536, 48)
  const float* b_dt = (const float*)d_in[6];    // (1536,)
  const float* A_log = (const float*)d_in[7];   // (1536, 16)
  const float* D_param = (const float*)d_in[8]; // (1536,)
  const float* W_out = (const float*)d_in[9];   // (768, 1536)
  float* out = (float*)d_out;                   // (2048, 768)

  // ---- workspace layout (fp32 region, then bf16 hi/lo region) ----
  float* ws = (float*)d_ws;
  float* xz = ws;                            // 2048*3072
  float* xbc = xz + SEQ * 2 * D_INNER;       // 2048*1536
  float* xdbl = xbc + SEQ * D_INNER;         // 2048*80
  float* aprod = xdbl + SEQ * 80;            // NC*DN
  float* hloc = aprod + NC * DN;             // NC*DN
  float* hstart = hloc + NC * DN;            // NC*DN

  ushort* x_hi = (ushort*)(hstart + NC * DN);       // 2048*768
  ushort* x_lo = x_hi + SEQ * D_MODEL;
  ushort* wi_hi = x_lo + SEQ * D_MODEL;             // 3072*768
  ushort* wi_lo = wi_hi + 2 * D_INNER * D_MODEL;
  ushort* wo_hi = wi_lo + 2 * D_INNER * D_MODEL;    // 768*1536
  ushort* wo_lo = wo_hi + D_MODEL * D_INNER;
  ushort* ym_hi = wo_lo + D_MODEL * D_INNER;        // 2048*1536
  ushort* ym_lo = ym_hi + SEQ * D_INNER;

  const dim3 blk(256);

  // ---- pre-split x, W_in, W_out into bf16 hi/lo (single fused launch) ----
  const int n0v = SEQ * D_MODEL / 4;            // 393216
  const int n1v = 2 * D_INNER * D_MODEL / 4;    // 589824
  const int n2v = D_MODEL * D_INNER / 4;        // 294912
  split3_bf16_kernel<<<dim3((n0v + n1v + n2v) / 256), blk, 0, stream>>>(
      x, x_hi, x_lo, n0v, W_in, wi_hi, wi_lo, n1v, W_out, wo_hi, wo_lo);

  // xz = x @ W_in^T   (2048 x 3072), MFMA pre-split + swizzled gload_lds
  gemm_mfma_presplit<128, 64><<<dim3(2 * D_INNER / 64, SEQ / 128), blk, 0, stream>>>(
      x_hi, x_lo, D_MODEL, wi_hi, wi_lo, D_MODEL, xz, 2 * D_INNER, D_MODEL);

  // xbc = silu(causal_conv(xb) + conv_b); also zeroes xdbl for the atomics
  conv_silu_kernel<<<dim3(SEQ * D_INNER / 1024), blk, 0, stream>>>(
      xz, conv_w, conv_b, xbc, xdbl);

  // xdbl += split-K chunks of xbc @ W_x^T (atomic fp32, native on gfx950)
  gemm2_splitk<<<dim3(SEQ / 64, KS), blk, 0, stream>>>(xbc, W_x, xdbl);

  // chunked scan with fused dt-projection (softplus(xdbl[:, :48] @ W_dt^T + b))
  scan_part1<<<dim3(D_INNER / 16, NC), blk, 0, stream>>>(
      xdbl, xbc, W_dt, b_dt, A_log, aprod, hloc);
  scan_combine<<<dim3(DN / 256), blk, 0, stream>>>(aprod, hloc, hstart);
  scan_part3<<<dim3(D_INNER / 16, NC), blk, 0, stream>>>(
      xdbl, xbc, xz, W_dt, b_dt, A_log, D_param, hstart, ym_hi, ym_lo);

  // out = ym @ W_out^T   (2048 x 768), MFMA pre-split + swizzled gload_lds
  gemm_mfma_presplit<64, 64><<<dim3(D_MODEL / 64, SEQ / 64), blk, 0, stream>>>(
      ym_hi, ym_lo, D_INNER, wo_hi, wo_lo, D_INNER, out, D_MODEL, D_INNER);
}